// Round 7
// baseline (437.659 us; speedup 1.0000x reference)
//
#include <hip/hip_runtime.h>
#include <math.h>

typedef unsigned long long u64;

#define N_PTS 12000
#define KNN 16
#define TJ 256     // candidate tile size (LDS)
#define Q 2        // queries per wave
#define WPB 4      // waves per block
#define NTILES ((N_PTS + TJ - 1) / TJ)   // 47
#define TAU_TILES 8                      // sample = first 2048 points -> tau
#define CAP 384                          // survivor capacity; P(overflow) ~ 1e-11/query

// LDS tile layout: row-major, stride exactly 16 floats, XOR-swizzled:
// logical float4-group g of point jl lives at physical group g ^ ((jl>>1)&3).
// => every aligned 8-lane group covers 8 distinct bank-quads on b128 reads
//    AND on staging writes: conflict-free (bank = 16*(jl&1) + 4*(g^t)).

// ---------------------------------------------------------------------------
// Kernel 1: encoders. feats = tanh(x@Wf + bf); coords = tanh(x@Wl + bl);
// sq[i] = sum(coords[i]^2). One wave per row.
// ---------------------------------------------------------------------------
__global__ __launch_bounds__(256) void encoder_kernel(
    const float* __restrict__ x, const float* __restrict__ Wf, const float* __restrict__ bf,
    const float* __restrict__ Wl, const float* __restrict__ bl,
    float* __restrict__ feats, float* __restrict__ coords, float* __restrict__ sq)
{
  const int wave = threadIdx.x >> 6;
  const int lane = threadIdx.x & 63;
  const int i = blockIdx.x * 4 + wave;
  if (i >= N_PTS) return;
  float xv = x[i * 64 + lane];
  float accf = bf[lane];
  float accc = bl[lane & 15];
  #pragma unroll
  for (int k = 0; k < 64; ++k) {
    float xk = __shfl(xv, k);
    accf = fmaf(xk, Wf[k * 64 + lane], accf);
    accc = fmaf(xk, Wl[k * 16 + (lane & 15)], accc);
  }
  feats[i * 64 + lane] = tanhf(accf);
  float c = tanhf(accc);
  float cc = (lane < 16) ? c * c : 0.0f;
  cc += __shfl_xor(cc, 1);
  cc += __shfl_xor(cc, 2);
  cc += __shfl_xor(cc, 4);
  cc += __shfl_xor(cc, 8);
  if (lane < 16) coords[i * 16 + lane] = c;
  if (lane == 0) sq[i] = cc;
}

// ---------------------------------------------------------------------------
// Branchless replace-max inserts into small u64 key tables. Keys
// (f32bits(d2)<<32)|j are globally unique; each key offered at most once, so
// the equality-match hits exactly one slot. Sentinels (0x7F00000t<<32) are
// distinct and larger than any real key; ~0ull matches nothing.
// ---------------------------------------------------------------------------
__device__ __forceinline__ void ins8(u64 key, u64* k8, u64& kmax) {
  const u64 om = (key < kmax) ? kmax : ~0ull;
  #pragma unroll
  for (int t = 0; t < 8; ++t)
    k8[t] = (k8[t] == om) ? key : k8[t];
  u64 a = k8[0] > k8[1] ? k8[0] : k8[1];
  u64 b = k8[2] > k8[3] ? k8[2] : k8[3];
  u64 c = k8[4] > k8[5] ? k8[4] : k8[5];
  u64 d = k8[6] > k8[7] ? k8[6] : k8[7];
  a = a > b ? a : b;
  c = c > d ? c : d;
  kmax = a > c ? a : c;
}

__device__ __forceinline__ void ins6(u64 key, u64* k6, u64& kmax) {
  const u64 om = (key < kmax) ? kmax : ~0ull;
  #pragma unroll
  for (int t = 0; t < 6; ++t)
    k6[t] = (k6[t] == om) ? key : k6[t];
  u64 a = k6[0] > k6[1] ? k6[0] : k6[1];
  u64 b = k6[2] > k6[3] ? k6[2] : k6[3];
  u64 c = k6[4] > k6[5] ? k6[4] : k6[5];
  a = a > b ? a : b;
  kmax = a > c ? a : c;
}

__device__ __forceinline__ u64 shflx_u64(u64 v, int off) {
  int lo = __shfl_xor((int)(unsigned)v, off);
  int hi = __shfl_xor((int)(unsigned)(v >> 32), off);
  return ((u64)(unsigned)hi << 32) | (unsigned)lo;
}

__device__ __forceinline__ u64 minbfly(u64 m) {
  #pragma unroll
  for (int off = 32; off >= 1; off >>= 1) {
    u64 o = shflx_u64(m, off);
    m = (o < m) ? o : m;
  }
  return m;
}

// ---------------------------------------------------------------------------
// Kernel 2: KNN (K=16, self excluded) + gaussian aggregation.
// Phase A: top-16 of first 2048 points -> tau_q (sound upper bound).
// Phase B: full scan; d2 <= tau_q pushed into per-query LDS survivor buffer.
// Phase C: exact top-16 of survivors (<=6 offers/lane into 6-slot table:
//   eviction impossible -> exact). Only failure mode is overflow -> flag.
// ---------------------------------------------------------------------------
__global__ __launch_bounds__(256) void knn_agg_kernel(
    const float* __restrict__ coords, const float* __restrict__ sq,
    const float* __restrict__ feats, float* __restrict__ agg,
    int* __restrict__ flags)
{
  __shared__ float cT[TJ * 16];           // 16384 B, swizzled
  __shared__ float sqs[TJ];               //  1024 B
  __shared__ u64 sbuf[WPB * Q][CAP];      // 24576 B
  __shared__ int scnt[WPB * Q];           //    32 B

  const int lane = threadIdx.x & 63;
  const int wave = threadIdx.x >> 6;
  const int qbase = blockIdx.x * (WPB * Q) + wave * Q;
  const int wq0 = wave * Q + 0;
  const int wq1 = wave * Q + 1;

  if (threadIdx.x < WPB * Q) scnt[threadIdx.x] = 0;

  float ci[Q][16], sqi[Q];
  #pragma unroll
  for (int q = 0; q < Q; ++q) {
    #pragma unroll
    for (int d = 0; d < 16; ++d) ci[q][d] = coords[(qbase + q) * 16 + d];
    sqi[q] = sq[qbase + q];
  }

  const int s_jl = threadIdx.x >> 2;            // 0..63
  const int s_g  = threadIdx.x & 3;
  const int s_p  = s_g ^ ((s_jl >> 1) & 3);     // physical group (swizzle)
  const int rt   = (lane >> 1) & 3;             // read-side swizzle term

  // ===================== Phase A: tau from first 2048 pts ====================
  u64 k8[Q][8], kmax[Q];
  #pragma unroll
  for (int q = 0; q < Q; ++q) {
    #pragma unroll
    for (int t = 0; t < 8; ++t)
      k8[q][t] = ((u64)(0x7F000000u + t) << 32);
    kmax[q] = ((u64)0x7F000007u << 32);
  }

  for (int tile = 0; tile < TAU_TILES; ++tile) {
    const int j0 = tile * TJ;
    __syncthreads();
    #pragma unroll
    for (int p = 0; p < 4; ++p) {
      const int jl = s_jl + p * 64;             // (jl>>1)&3 invariant in p
      const int j = j0 + jl;
      float4 v = make_float4(0.f, 0.f, 0.f, 0.f);
      if (j < N_PTS) v = ((const float4*)(coords + j * 16))[s_g];
      *(float4*)&cT[jl * 16 + 4 * s_p] = v;
    }
    sqs[threadIdx.x] = (j0 + (int)threadIdx.x < N_PTS) ? sq[j0 + threadIdx.x] : 0.0f;
    __syncthreads();

    float dq[Q][4];
    #pragma unroll
    for (int h = 0; h < 4; ++h) {
      const int jl = h * 64 + lane;
      const int j = j0 + jl;
      const float sqj = sqs[jl];
      float cj[16];
      *(float4*)&cj[0]  = *(float4*)&cT[jl * 16 + 4 * (0 ^ rt)];
      *(float4*)&cj[4]  = *(float4*)&cT[jl * 16 + 4 * (1 ^ rt)];
      *(float4*)&cj[8]  = *(float4*)&cT[jl * 16 + 4 * (2 ^ rt)];
      *(float4*)&cj[12] = *(float4*)&cT[jl * 16 + 4 * (3 ^ rt)];
      float dot0 = 0.0f, dot1 = 0.0f;
      #pragma unroll
      for (int d = 0; d < 16; ++d) {
        dot0 = fmaf(ci[0][d], cj[d], dot0);
        dot1 = fmaf(ci[1][d], cj[d], dot1);
      }
      float d20 = fmaxf(fmaf(-2.0f, dot0, sqi[0] + sqj), 0.0f);
      float d21 = fmaxf(fmaf(-2.0f, dot1, sqi[1] + sqj), 0.0f);
      if (j == qbase + 0) d20 = INFINITY;
      if (j == qbase + 1) d21 = INFINITY;
      dq[0][h] = d20;
      dq[1][h] = d21;
    }
    #pragma unroll
    for (int q = 0; q < Q; ++q) {
      const float a = dq[q][0], b = dq[q][1], c = dq[q][2], d = dq[q][3];
      const float lo1 = fminf(a, b), lo2 = fminf(c, d);
      const int h1 = (a <= b) ? 0 : 1;
      const int h2 = (c <= d) ? 2 : 3;
      const float dm = fminf(lo1, lo2);
      const int hm = (lo1 <= lo2) ? h1 : h2;
      const u64 key = ((u64)__float_as_uint(dm) << 32) | (unsigned)(j0 + hm * 64 + lane);
      ins8(key, k8[q], kmax[q]);
    }
  }

  float tau[Q];
  #pragma unroll
  for (int q = 0; q < Q; ++q) {
    u64 lmin = k8[q][0];
    #pragma unroll
    for (int t = 1; t < 8; ++t) lmin = (k8[q][t] < lmin) ? k8[q][t] : lmin;
    u64 m = 0;
    for (int r = 0; r < KNN; ++r) {
      m = minbfly(lmin);
      if (lmin == m) {
        #pragma unroll
        for (int t = 0; t < 8; ++t) k8[q][t] = (k8[q][t] == m) ? ~0ull : k8[q][t];
        lmin = k8[q][0];
        #pragma unroll
        for (int t = 1; t < 8; ++t) lmin = (k8[q][t] < lmin) ? k8[q][t] : lmin;
      }
    }
    tau[q] = __uint_as_float((unsigned)(m >> 32));  // 16th-smallest of sample: sound
  }

  // ===================== Phase B: gated scan, push survivors =================
  for (int tile = 0; tile < NTILES; ++tile) {
    const int j0 = tile * TJ;
    __syncthreads();
    #pragma unroll
    for (int p = 0; p < 4; ++p) {
      const int jl = s_jl + p * 64;
      const int j = j0 + jl;
      float4 v = make_float4(0.f, 0.f, 0.f, 0.f);
      if (j < N_PTS) v = ((const float4*)(coords + j * 16))[s_g];
      *(float4*)&cT[jl * 16 + 4 * s_p] = v;
    }
    sqs[threadIdx.x] = (j0 + (int)threadIdx.x < N_PTS) ? sq[j0 + threadIdx.x] : 0.0f;
    __syncthreads();

    #pragma unroll
    for (int h = 0; h < 4; ++h) {
      const int jl = h * 64 + lane;
      const int j = j0 + jl;
      const float sqj = sqs[jl];
      float cj[16];
      *(float4*)&cj[0]  = *(float4*)&cT[jl * 16 + 4 * (0 ^ rt)];
      *(float4*)&cj[4]  = *(float4*)&cT[jl * 16 + 4 * (1 ^ rt)];
      *(float4*)&cj[8]  = *(float4*)&cT[jl * 16 + 4 * (2 ^ rt)];
      *(float4*)&cj[12] = *(float4*)&cT[jl * 16 + 4 * (3 ^ rt)];
      float dot0 = 0.0f, dot1 = 0.0f;
      #pragma unroll
      for (int d = 0; d < 16; ++d) {
        dot0 = fmaf(ci[0][d], cj[d], dot0);
        dot1 = fmaf(ci[1][d], cj[d], dot1);
      }
      float d20 = fmaxf(fmaf(-2.0f, dot0, sqi[0] + sqj), 0.0f);
      float d21 = fmaxf(fmaf(-2.0f, dot1, sqi[1] + sqj), 0.0f);
      if (j == qbase + 0 || j >= N_PTS) d20 = INFINITY;
      if (j == qbase + 1 || j >= N_PTS) d21 = INFINITY;

      const bool g0 = (d20 <= tau[0]);
      if (__any(g0)) {
        if (g0) {
          const int p = atomicAdd(&scnt[wq0], 1);
          if (p < CAP)
            sbuf[wq0][p] = ((u64)__float_as_uint(d20) << 32) | (unsigned)j;
        }
      }
      const bool g1 = (d21 <= tau[1]);
      if (__any(g1)) {
        if (g1) {
          const int p = atomicAdd(&scnt[wq1], 1);
          if (p < CAP)
            sbuf[wq1][p] = ((u64)__float_as_uint(d21) << 32) | (unsigned)j;
        }
      }
    }
  }

  // ===================== Phase C: exact top-16 of survivors ==================
  #pragma unroll
  for (int q = 0; q < Q; ++q) {
    const int wq = wave * Q + q;
    const int cq = scnt[wq];               // wave-uniform (own wave's pushes)
    const int nread = (cq < CAP) ? cq : CAP;

    u64 k6[6];
    #pragma unroll
    for (int t = 0; t < 6; ++t) k6[t] = ((u64)(0x7F000000u + t) << 32);
    u64 kmax6 = ((u64)0x7F000005u << 32);

    #pragma unroll
    for (int t = 0; t < CAP / 64; ++t) {   // <= 6 offers per lane: no eviction possible
      const int idx = t * 64 + lane;
      const u64 key = (idx < nread) ? sbuf[wq][idx] : ~0ull;
      ins6(key, k6, kmax6);
    }

    u64 lmin = k6[0];
    #pragma unroll
    for (int t = 1; t < 6; ++t) lmin = (k6[t] < lmin) ? k6[t] : lmin;

    float aggv = 0.0f;
    for (int r = 0; r < KNN; ++r) {
      const u64 m = minbfly(lmin);
      if (lmin == m) {
        #pragma unroll
        for (int t = 0; t < 6; ++t) k6[t] = (k6[t] == m) ? ~0ull : k6[t];
        lmin = k6[0];
        #pragma unroll
        for (int t = 1; t < 6; ++t) lmin = (k6[t] < lmin) ? k6[t] : lmin;
      }
      const unsigned hi = (unsigned)(m >> 32);
      const bool ok = hi < 0x7F000000u;
      const float w = ok ? expf(-__uint_as_float(hi)) : 0.0f;
      const int jj = ok ? (int)(unsigned)(m & 0xFFFFFFFFull) : 0;
      aggv = fmaf(w, feats[jj * 64 + lane], aggv);
    }
    agg[(qbase + q) * 64 + lane] = aggv;
    if (lane == 0) flags[qbase + q] = (cq > CAP);   // overflow is the only failure mode
  }
}

// ---------------------------------------------------------------------------
// Kernel 2b: exact fallback for flagged queries (expected: zero).
// Fast path: one strided pass, two per-lane top-8 half-tables.
// Slow exact path only if the fast path's own eviction flag fires.
// ---------------------------------------------------------------------------
__global__ __launch_bounds__(256) void knn_fixup_kernel(
    const float* __restrict__ coords, const float* __restrict__ sq,
    const float* __restrict__ feats, const int* __restrict__ flags,
    float* __restrict__ agg)
{
  const int wave = threadIdx.x >> 6;
  const int lane = threadIdx.x & 63;
  const int i = blockIdx.x * 4 + wave;
  if (i >= N_PTS) return;
  if (!flags[i]) return;
  float ci[16];
  #pragma unroll
  for (int d = 0; d < 16; ++d) ci[d] = coords[i * 16 + d];
  const float sqi = sq[i];

  u64 k8a[8], k8b[8], kmaxA, kmaxB;
  #pragma unroll
  for (int t = 0; t < 8; ++t) {
    k8a[t] = ((u64)(0x7F000000u + t) << 32);
    k8b[t] = ((u64)(0x7F000000u + t) << 32);
  }
  kmaxA = ((u64)0x7F000007u << 32);
  kmaxB = ((u64)0x7F000007u << 32);

  const int niter = (N_PTS + 63) / 64;  // 188
  for (int t = 0; t < niter; ++t) {
    const int j = t * 64 + lane;
    float4 c0 = make_float4(0,0,0,0), c1 = c0, c2 = c0, c3 = c0;
    float sqj = 0.0f;
    if (j < N_PTS) {
      const float4* cp = (const float4*)(coords + j * 16);
      c0 = cp[0]; c1 = cp[1]; c2 = cp[2]; c3 = cp[3];
      sqj = sq[j];
    }
    float dot = ci[0]*c0.x + ci[1]*c0.y + ci[2]*c0.z + ci[3]*c0.w
              + ci[4]*c1.x + ci[5]*c1.y + ci[6]*c1.z + ci[7]*c1.w
              + ci[8]*c2.x + ci[9]*c2.y + ci[10]*c2.z + ci[11]*c2.w
              + ci[12]*c3.x + ci[13]*c3.y + ci[14]*c3.z + ci[15]*c3.w;
    float d2 = fmaxf(fmaf(-2.0f, dot, sqi + sqj), 0.0f);
    const unsigned hi = (j == i || j >= N_PTS) ? 0xFFFFFFFFu : __float_as_uint(d2);
    const u64 key = ((u64)hi << 32) | (unsigned)j;
    if (t & 1) ins8(key, k8a, kmaxA);
    else       ins8(key, k8b, kmaxB);
  }

  u64 tab[16];
  #pragma unroll
  for (int t = 0; t < 8; ++t) { tab[t] = k8a[t]; tab[8 + t] = k8b[t]; }
  u64 lmin = tab[0];
  #pragma unroll
  for (int t = 1; t < 16; ++t) lmin = (tab[t] < lmin) ? tab[t] : lmin;

  float aggv = 0.0f;
  u64 T16 = 0;
  for (int r = 0; r < KNN; ++r) {
    const u64 m = minbfly(lmin);
    if (lmin == m) {
      #pragma unroll
      for (int t = 0; t < 16; ++t) tab[t] = (tab[t] == m) ? ~0ull : tab[t];
      lmin = tab[0];
      #pragma unroll
      for (int t = 1; t < 16; ++t) lmin = (tab[t] < lmin) ? tab[t] : lmin;
    }
    const unsigned hi = (unsigned)(m >> 32);
    const bool ok = hi < 0x7F000000u;
    const float w = ok ? expf(-__uint_as_float(hi)) : 0.0f;
    const int jj = ok ? (int)(unsigned)(m & 0xFFFFFFFFull) : 0;
    aggv = fmaf(w, feats[jj * 64 + lane], aggv);
    T16 = m;
  }

  if (__any((kmaxA < T16) || (kmaxB < T16))) {
    aggv = 0.0f;
    u64 prev = 0;
    for (int r = 0; r < KNN; ++r) {
      u64 best = ~0ull;
      for (int j = lane; j < N_PTS; j += 64) {
        float dot = 0.0f;
        #pragma unroll
        for (int d = 0; d < 16; ++d) dot = fmaf(ci[d], coords[j * 16 + d], dot);
        const float d2 = fmaxf(fmaf(-2.0f, dot, sqi + sq[j]), 0.0f);
        const unsigned hi = (j == i) ? 0xFFFFFFFFu : __float_as_uint(d2);
        const u64 key = ((u64)hi << 32) | (unsigned)j;
        const bool cand = (r == 0) || (key > prev);
        if (cand && key < best) best = key;
      }
      const u64 m = minbfly(best);
      prev = m;
      const unsigned hi = (unsigned)(m >> 32);
      const bool ok = hi < 0x7F000000u;
      const float w = ok ? expf(-__uint_as_float(hi)) : 0.0f;
      const int jj = ok ? (int)(unsigned)(m & 0xFFFFFFFFull) : 0;
      aggv = fmaf(w, feats[jj * 64 + lane], aggv);
    }
  }
  agg[i * 64 + lane] = aggv;
}

// ---------------------------------------------------------------------------
// Kernel 3: out = concat(feats, agg) @ W_out + b_out.  Wave per row.
// ---------------------------------------------------------------------------
__global__ __launch_bounds__(256) void out_kernel(
    const float* __restrict__ feats, const float* __restrict__ agg,
    const float* __restrict__ Wo, const float* __restrict__ bo,
    float* __restrict__ out)
{
  const int idx = blockIdx.x * 256 + threadIdx.x;
  const int i = idx >> 6, o = idx & 63;
  if (i >= N_PTS) return;
  float acc = bo[o];
  #pragma unroll
  for (int f = 0; f < 64; ++f)
    acc = fmaf(feats[i * 64 + f], Wo[f * 64 + o], acc);
  #pragma unroll
  for (int f = 0; f < 64; ++f)
    acc = fmaf(agg[i * 64 + f], Wo[(64 + f) * 64 + o], acc);
  out[i * 64 + o] = acc;
}

extern "C" void kernel_launch(void* const* d_in, const int* in_sizes, int n_in,
                              void* d_out, int out_size, void* d_ws, size_t ws_size,
                              hipStream_t stream) {
  const float* x  = (const float*)d_in[0];
  const float* Wf = (const float*)d_in[1];
  const float* bf = (const float*)d_in[2];
  const float* Wl = (const float*)d_in[3];
  const float* bl = (const float*)d_in[4];
  const float* Wo = (const float*)d_in[5];
  const float* bo = (const float*)d_in[6];
  float* out = (float*)d_out;

  char* ws = (char*)d_ws;
  float* feats  = (float*)(ws);                    // 3,072,000 B
  float* coords = (float*)(ws + 3072000);          //   768,000 B
  float* sqv    = (float*)(ws + 3840000);          //    48,000 B
  float* agg    = (float*)(ws + 3888000);          // 3,072,000 B
  int*   flags  = (int*)  (ws + 6960000);          //    48,000 B

  encoder_kernel<<<3000, 256, 0, stream>>>(x, Wf, bf, Wl, bl, feats, coords, sqv);
  knn_agg_kernel<<<N_PTS / (WPB * Q), 256, 0, stream>>>(coords, sqv, feats, agg, flags);
  knn_fixup_kernel<<<3000, 256, 0, stream>>>(coords, sqv, feats, flags, agg);
  out_kernel<<<3000, 256, 0, stream>>>(feats, agg, Wo, bo, out);
}

// Round 8
// 312.970 us; speedup vs baseline: 1.3984x; 1.3984x over previous
//
#include <hip/hip_runtime.h>
#include <math.h>

typedef unsigned long long u64;

#define N_PTS 12000
#define KNN 16
#define TJ 256     // candidate tile size (LDS)
#define Q 4        // queries per wave
#define WPB 4      // waves per block
#define NTILES ((N_PTS + TJ - 1) / TJ)   // 47
#define TAU_TILES 8                      // sample = first 2048 points -> tau
#define CAP 320                          // survivor capacity (mean ~111); 5 offers/lane max
#define SSTRIDE 20                       // LDS row stride in floats (measured best so far)

// ---------------------------------------------------------------------------
// Kernel 1: encoders. feats = tanh(x@Wf + bf); coords = tanh(x@Wl + bl);
// sq[i] = sum(coords[i]^2). One wave per row.
// ---------------------------------------------------------------------------
__global__ __launch_bounds__(256) void encoder_kernel(
    const float* __restrict__ x, const float* __restrict__ Wf, const float* __restrict__ bf,
    const float* __restrict__ Wl, const float* __restrict__ bl,
    float* __restrict__ feats, float* __restrict__ coords, float* __restrict__ sq)
{
  const int wave = threadIdx.x >> 6;
  const int lane = threadIdx.x & 63;
  const int i = blockIdx.x * 4 + wave;
  if (i >= N_PTS) return;
  float xv = x[i * 64 + lane];
  float accf = bf[lane];
  float accc = bl[lane & 15];
  #pragma unroll
  for (int k = 0; k < 64; ++k) {
    float xk = __shfl(xv, k);
    accf = fmaf(xk, Wf[k * 64 + lane], accf);
    accc = fmaf(xk, Wl[k * 16 + (lane & 15)], accc);
  }
  feats[i * 64 + lane] = tanhf(accf);
  float c = tanhf(accc);
  float cc = (lane < 16) ? c * c : 0.0f;
  cc += __shfl_xor(cc, 1);
  cc += __shfl_xor(cc, 2);
  cc += __shfl_xor(cc, 4);
  cc += __shfl_xor(cc, 8);
  if (lane < 16) coords[i * 16 + lane] = c;
  if (lane == 0) sq[i] = cc;
}

// ---------------------------------------------------------------------------
// u64-key helpers. Keys (f32bits(d2)<<32)|j are globally unique; sentinels
// (0x7F00000t<<32) exceed any real key; ~0ull matches no slot.
// ---------------------------------------------------------------------------
__device__ __forceinline__ void ins5(u64 key, u64* k5, u64& kmax) {
  const u64 om = (key < kmax) ? kmax : ~0ull;
  #pragma unroll
  for (int t = 0; t < 5; ++t)
    k5[t] = (k5[t] == om) ? key : k5[t];
  u64 a = k5[0] > k5[1] ? k5[0] : k5[1];
  u64 b = k5[2] > k5[3] ? k5[2] : k5[3];
  a = a > b ? a : b;
  kmax = a > k5[4] ? a : k5[4];
}

__device__ __forceinline__ void ins8(u64 key, u64* k8, u64& kmax) {
  const u64 om = (key < kmax) ? kmax : ~0ull;
  #pragma unroll
  for (int t = 0; t < 8; ++t)
    k8[t] = (k8[t] == om) ? key : k8[t];
  u64 a = k8[0] > k8[1] ? k8[0] : k8[1];
  u64 b = k8[2] > k8[3] ? k8[2] : k8[3];
  u64 c = k8[4] > k8[5] ? k8[4] : k8[5];
  u64 d = k8[6] > k8[7] ? k8[6] : k8[7];
  a = a > b ? a : b;
  c = c > d ? c : d;
  kmax = a > c ? a : c;
}

__device__ __forceinline__ u64 shflx_u64(u64 v, int off) {
  int lo = __shfl_xor((int)(unsigned)v, off);
  int hi = __shfl_xor((int)(unsigned)(v >> 32), off);
  return ((u64)(unsigned)hi << 32) | (unsigned)lo;
}

__device__ __forceinline__ u64 minbfly(u64 m) {
  #pragma unroll
  for (int off = 32; off >= 1; off >>= 1) {
    u64 o = shflx_u64(m, off);
    m = (o < m) ? o : m;
  }
  return m;
}

// ---------------------------------------------------------------------------
// Kernel 2: KNN (K=16, self excluded) + gaussian aggregation. Wave = 4 queries.
// Phase A: per-lane running min over first 2048 pts (1 fmin/cand/q); tau_q =
//   16th-order-stat of the 64 lane minima (wave bitonic sort). SOUND: the 16
//   smallest lane-minima are 16 distinct candidates => max of them >= global
//   16th-smallest.
// Phase B: full scan; d2 <= tau_q pushes u16 index into per-query LDS buffer.
// Phase C: recompute survivor d2 (identical fmaf chain => bit-identical),
//   exact top-16 via 5-slot tables (<=5 offers/lane: eviction impossible) +
//   minbfly merge. Only failure mode = overflow -> flag -> fixup kernel.
// ---------------------------------------------------------------------------
__global__ __launch_bounds__(256) void knn_agg_kernel(
    const float* __restrict__ coords, const float* __restrict__ sq,
    const float* __restrict__ feats, float* __restrict__ agg,
    int* __restrict__ flags)
{
  __shared__ float cT[TJ * SSTRIDE];              // 20480 B
  __shared__ float sqs[TJ];                       //  1024 B
  __shared__ unsigned short sbuf[WPB * Q][CAP];   // 10240 B
  __shared__ int scnt[WPB * Q];                   //    64 B

  const int lane = threadIdx.x & 63;
  const int wave = threadIdx.x >> 6;
  const int qbase = blockIdx.x * (WPB * Q) + wave * Q;

  if (threadIdx.x < WPB * Q) scnt[threadIdx.x] = 0;

  float ci[Q][16], sqi[Q];
  #pragma unroll
  for (int q = 0; q < Q; ++q) {
    #pragma unroll
    for (int d = 0; d < 16; ++d) ci[q][d] = coords[(qbase + q) * 16 + d];
    sqi[q] = sq[qbase + q];
  }

  const int s_jl = threadIdx.x >> 2;  // 0..63
  const int s_g  = threadIdx.x & 3;

  // ===================== Phase A: per-lane min over 2048 pts =================
  float lmind[Q];
  #pragma unroll
  for (int q = 0; q < Q; ++q) lmind[q] = INFINITY;

  for (int tile = 0; tile < TAU_TILES; ++tile) {
    const int j0 = tile * TJ;
    __syncthreads();
    #pragma unroll
    for (int p = 0; p < 4; ++p) {
      const int jl = s_jl + p * 64;
      const int j = j0 + jl;
      float4 v = make_float4(0.f, 0.f, 0.f, 0.f);
      if (j < N_PTS) v = ((const float4*)(coords + j * 16))[s_g];
      *(float4*)&cT[jl * SSTRIDE + 4 * s_g] = v;
    }
    sqs[threadIdx.x] = (j0 + (int)threadIdx.x < N_PTS) ? sq[j0 + threadIdx.x] : 0.0f;
    __syncthreads();

    #pragma unroll
    for (int h = 0; h < 4; ++h) {
      const int jl = h * 64 + lane;
      const int j = j0 + jl;
      const float sqj = sqs[jl];
      float cj[16];
      *(float4*)&cj[0]  = *(float4*)&cT[jl * SSTRIDE + 0];
      *(float4*)&cj[4]  = *(float4*)&cT[jl * SSTRIDE + 4];
      *(float4*)&cj[8]  = *(float4*)&cT[jl * SSTRIDE + 8];
      *(float4*)&cj[12] = *(float4*)&cT[jl * SSTRIDE + 12];
      #pragma unroll
      for (int q = 0; q < Q; ++q) {
        float dot = 0.0f;
        #pragma unroll
        for (int d = 0; d < 16; ++d) dot = fmaf(ci[q][d], cj[d], dot);
        float d2 = fmaxf(fmaf(-2.0f, dot, sqi[q] + sqj), 0.0f);
        if (j == qbase + q) d2 = INFINITY;
        lmind[q] = fminf(lmind[q], d2);
      }
    }
  }

  // tau_q = 16th-smallest of the 64 lane minima (bitonic sort, take lane 15)
  float tau[Q];
  #pragma unroll
  for (int q = 0; q < Q; ++q) {
    float v = lmind[q];
    #pragma unroll
    for (int k = 2; k <= 64; k <<= 1) {
      #pragma unroll
      for (int s = k >> 1; s >= 1; s >>= 1) {
        const float o = __shfl_xor(v, s);
        const bool keepMin = (((lane & s) == 0) == ((lane & k) == 0));
        const float mn = fminf(v, o), mx = fmaxf(v, o);
        v = keepMin ? mn : mx;
      }
    }
    tau[q] = __shfl(v, 15);
  }

  // ===================== Phase B: gated scan, push survivor indices =========
  for (int tile = 0; tile < NTILES; ++tile) {
    const int j0 = tile * TJ;
    __syncthreads();
    #pragma unroll
    for (int p = 0; p < 4; ++p) {
      const int jl = s_jl + p * 64;
      const int j = j0 + jl;
      float4 v = make_float4(0.f, 0.f, 0.f, 0.f);
      if (j < N_PTS) v = ((const float4*)(coords + j * 16))[s_g];
      *(float4*)&cT[jl * SSTRIDE + 4 * s_g] = v;
    }
    sqs[threadIdx.x] = (j0 + (int)threadIdx.x < N_PTS) ? sq[j0 + threadIdx.x] : 0.0f;
    __syncthreads();

    #pragma unroll
    for (int h = 0; h < 4; ++h) {
      const int jl = h * 64 + lane;
      const int j = j0 + jl;
      const float sqj = sqs[jl];
      float cj[16];
      *(float4*)&cj[0]  = *(float4*)&cT[jl * SSTRIDE + 0];
      *(float4*)&cj[4]  = *(float4*)&cT[jl * SSTRIDE + 4];
      *(float4*)&cj[8]  = *(float4*)&cT[jl * SSTRIDE + 8];
      *(float4*)&cj[12] = *(float4*)&cT[jl * SSTRIDE + 12];
      #pragma unroll
      for (int q = 0; q < Q; ++q) {
        float dot = 0.0f;
        #pragma unroll
        for (int d = 0; d < 16; ++d) dot = fmaf(ci[q][d], cj[d], dot);
        float d2 = fmaxf(fmaf(-2.0f, dot, sqi[q] + sqj), 0.0f);
        if (j == qbase + q || j >= N_PTS) d2 = INFINITY;
        if (d2 <= tau[q]) {                      // ~1.1 lanes/wave fire
          const int wq = wave * Q + q;
          const int p = atomicAdd(&scnt[wq], 1);
          if (p < CAP) sbuf[wq][p] = (unsigned short)j;
        }
      }
    }
  }

  // ===================== Phase C: exact top-16 of survivors ==================
  #pragma unroll
  for (int q = 0; q < Q; ++q) {
    const int wq = wave * Q + q;
    const int cq = scnt[wq];                     // own-wave pushes: wave-coherent
    const int nread = (cq < CAP) ? cq : CAP;

    u64 k5[5];
    #pragma unroll
    for (int t = 0; t < 5; ++t) k5[t] = ((u64)(0x7F000000u + t) << 32);
    u64 kmax5 = ((u64)0x7F000004u << 32);

    #pragma unroll
    for (int t = 0; t < CAP / 64; ++t) {         // <=5 offers/lane: no eviction
      const int idx = t * 64 + lane;
      u64 key = ~0ull;
      if (idx < nread) {
        const int jj = sbuf[wq][idx];
        const float4* cp = (const float4*)(coords + jj * 16);
        float cj[16];
        *(float4*)&cj[0]  = cp[0];
        *(float4*)&cj[4]  = cp[1];
        *(float4*)&cj[8]  = cp[2];
        *(float4*)&cj[12] = cp[3];
        float dot = 0.0f;
        #pragma unroll
        for (int d = 0; d < 16; ++d) dot = fmaf(ci[q][d], cj[d], dot);
        const float d2 = fmaxf(fmaf(-2.0f, dot, sqi[q] + sq[jj]), 0.0f);
        key = ((u64)__float_as_uint(d2) << 32) | (unsigned)jj;
      }
      ins5(key, k5, kmax5);
    }

    u64 lmin = k5[0];
    #pragma unroll
    for (int t = 1; t < 5; ++t) lmin = (k5[t] < lmin) ? k5[t] : lmin;

    float aggv = 0.0f;
    for (int r = 0; r < KNN; ++r) {
      const u64 m = minbfly(lmin);
      if (lmin == m) {
        #pragma unroll
        for (int t = 0; t < 5; ++t) k5[t] = (k5[t] == m) ? ~0ull : k5[t];
        lmin = k5[0];
        #pragma unroll
        for (int t = 1; t < 5; ++t) lmin = (k5[t] < lmin) ? k5[t] : lmin;
      }
      const unsigned hi = (unsigned)(m >> 32);
      const bool ok = hi < 0x7F000000u;
      const float w = ok ? expf(-__uint_as_float(hi)) : 0.0f;
      const int jj = ok ? (int)(unsigned)(m & 0xFFFFFFFFull) : 0;
      aggv = fmaf(w, feats[jj * 64 + lane], aggv);
    }
    agg[(qbase + q) * 64 + lane] = aggv;
    if (lane == 0) flags[qbase + q] = (cq > CAP);
  }
}

// ---------------------------------------------------------------------------
// Kernel 2b: exact fallback for flagged queries (expected: zero).
// ---------------------------------------------------------------------------
__global__ __launch_bounds__(256) void knn_fixup_kernel(
    const float* __restrict__ coords, const float* __restrict__ sq,
    const float* __restrict__ feats, const int* __restrict__ flags,
    float* __restrict__ agg)
{
  const int wave = threadIdx.x >> 6;
  const int lane = threadIdx.x & 63;
  const int i = blockIdx.x * 4 + wave;
  if (i >= N_PTS) return;
  if (!flags[i]) return;
  float ci[16];
  #pragma unroll
  for (int d = 0; d < 16; ++d) ci[d] = coords[i * 16 + d];
  const float sqi = sq[i];

  u64 k8a[8], k8b[8], kmaxA, kmaxB;
  #pragma unroll
  for (int t = 0; t < 8; ++t) {
    k8a[t] = ((u64)(0x7F000000u + t) << 32);
    k8b[t] = ((u64)(0x7F000000u + t) << 32);
  }
  kmaxA = ((u64)0x7F000007u << 32);
  kmaxB = ((u64)0x7F000007u << 32);

  const int niter = (N_PTS + 63) / 64;  // 188
  for (int t = 0; t < niter; ++t) {
    const int j = t * 64 + lane;
    float4 c0 = make_float4(0,0,0,0), c1 = c0, c2 = c0, c3 = c0;
    float sqj = 0.0f;
    if (j < N_PTS) {
      const float4* cp = (const float4*)(coords + j * 16);
      c0 = cp[0]; c1 = cp[1]; c2 = cp[2]; c3 = cp[3];
      sqj = sq[j];
    }
    float dot = ci[0]*c0.x + ci[1]*c0.y + ci[2]*c0.z + ci[3]*c0.w
              + ci[4]*c1.x + ci[5]*c1.y + ci[6]*c1.z + ci[7]*c1.w
              + ci[8]*c2.x + ci[9]*c2.y + ci[10]*c2.z + ci[11]*c2.w
              + ci[12]*c3.x + ci[13]*c3.y + ci[14]*c3.z + ci[15]*c3.w;
    float d2 = fmaxf(fmaf(-2.0f, dot, sqi + sqj), 0.0f);
    const unsigned hi = (j == i || j >= N_PTS) ? 0xFFFFFFFFu : __float_as_uint(d2);
    const u64 key = ((u64)hi << 32) | (unsigned)j;
    if (t & 1) ins8(key, k8a, kmaxA);
    else       ins8(key, k8b, kmaxB);
  }

  u64 tab[16];
  #pragma unroll
  for (int t = 0; t < 8; ++t) { tab[t] = k8a[t]; tab[8 + t] = k8b[t]; }
  u64 lmin = tab[0];
  #pragma unroll
  for (int t = 1; t < 16; ++t) lmin = (tab[t] < lmin) ? tab[t] : lmin;

  float aggv = 0.0f;
  u64 T16 = 0;
  for (int r = 0; r < KNN; ++r) {
    const u64 m = minbfly(lmin);
    if (lmin == m) {
      #pragma unroll
      for (int t = 0; t < 16; ++t) tab[t] = (tab[t] == m) ? ~0ull : tab[t];
      lmin = tab[0];
      #pragma unroll
      for (int t = 1; t < 16; ++t) lmin = (tab[t] < lmin) ? tab[t] : lmin;
    }
    const unsigned hi = (unsigned)(m >> 32);
    const bool ok = hi < 0x7F000000u;
    const float w = ok ? expf(-__uint_as_float(hi)) : 0.0f;
    const int jj = ok ? (int)(unsigned)(m & 0xFFFFFFFFull) : 0;
    aggv = fmaf(w, feats[jj * 64 + lane], aggv);
    T16 = m;
  }

  if (__any((kmaxA < T16) || (kmaxB < T16))) {
    aggv = 0.0f;
    u64 prev = 0;
    for (int r = 0; r < KNN; ++r) {
      u64 best = ~0ull;
      for (int j = lane; j < N_PTS; j += 64) {
        float dot = 0.0f;
        #pragma unroll
        for (int d = 0; d < 16; ++d) dot = fmaf(ci[d], coords[j * 16 + d], dot);
        const float d2 = fmaxf(fmaf(-2.0f, dot, sqi + sq[j]), 0.0f);
        const unsigned hi = (j == i) ? 0xFFFFFFFFu : __float_as_uint(d2);
        const u64 key = ((u64)hi << 32) | (unsigned)j;
        const bool cand = (r == 0) || (key > prev);
        if (cand && key < best) best = key;
      }
      const u64 m = minbfly(best);
      prev = m;
      const unsigned hi = (unsigned)(m >> 32);
      const bool ok = hi < 0x7F000000u;
      const float w = ok ? expf(-__uint_as_float(hi)) : 0.0f;
      const int jj = ok ? (int)(unsigned)(m & 0xFFFFFFFFull) : 0;
      aggv = fmaf(w, feats[jj * 64 + lane], aggv);
    }
  }
  agg[i * 64 + lane] = aggv;
}

// ---------------------------------------------------------------------------
// Kernel 3: out = concat(feats, agg) @ W_out + b_out.  Wave per row.
// ---------------------------------------------------------------------------
__global__ __launch_bounds__(256) void out_kernel(
    const float* __restrict__ feats, const float* __restrict__ agg,
    const float* __restrict__ Wo, const float* __restrict__ bo,
    float* __restrict__ out)
{
  const int idx = blockIdx.x * 256 + threadIdx.x;
  const int i = idx >> 6, o = idx & 63;
  if (i >= N_PTS) return;
  float acc = bo[o];
  #pragma unroll
  for (int f = 0; f < 64; ++f)
    acc = fmaf(feats[i * 64 + f], Wo[f * 64 + o], acc);
  #pragma unroll
  for (int f = 0; f < 64; ++f)
    acc = fmaf(agg[i * 64 + f], Wo[(64 + f) * 64 + o], acc);
  out[i * 64 + o] = acc;
}

extern "C" void kernel_launch(void* const* d_in, const int* in_sizes, int n_in,
                              void* d_out, int out_size, void* d_ws, size_t ws_size,
                              hipStream_t stream) {
  const float* x  = (const float*)d_in[0];
  const float* Wf = (const float*)d_in[1];
  const float* bf = (const float*)d_in[2];
  const float* Wl = (const float*)d_in[3];
  const float* bl = (const float*)d_in[4];
  const float* Wo = (const float*)d_in[5];
  const float* bo = (const float*)d_in[6];
  float* out = (float*)d_out;

  char* ws = (char*)d_ws;
  float* feats  = (float*)(ws);                    // 3,072,000 B
  float* coords = (float*)(ws + 3072000);          //   768,000 B
  float* sqv    = (float*)(ws + 3840000);          //    48,000 B
  float* agg    = (float*)(ws + 3888000);          // 3,072,000 B
  int*   flags  = (int*)  (ws + 6960000);          //    48,000 B

  encoder_kernel<<<3000, 256, 0, stream>>>(x, Wf, bf, Wl, bl, feats, coords, sqv);
  knn_agg_kernel<<<N_PTS / (WPB * Q), 256, 0, stream>>>(coords, sqv, feats, agg, flags);
  knn_fixup_kernel<<<3000, 256, 0, stream>>>(coords, sqv, feats, flags, agg);
  out_kernel<<<3000, 256, 0, stream>>>(feats, agg, Wo, bo, out);
}